// Round 1
// baseline (1267.118 us; speedup 1.0000x reference)
//
#include <hip/hip_runtime.h>
#include <hip/hip_bf16.h>

// Problem constants
#define Ecst 1024
#define Hh 16
#define Dd 64
#define Cc_ 64
#define Bb 4
#define Nn_ 4096
#define Mrows (Bb*Nn_)          // 16384 token rows
#define BNE (Bb*Nn_*Ecst)       // 16,777,216

typedef __attribute__((ext_vector_type(4))) float f32x4;
typedef __attribute__((ext_vector_type(8))) short short8;
typedef __attribute__((ext_vector_type(4))) unsigned short ushort4v;

__device__ __forceinline__ float bf2f(unsigned short u) {
    union { float f; unsigned int i; } x; x.i = ((unsigned int)u) << 16; return x.f;
}
__device__ __forceinline__ unsigned short f2bf(float f) {
    __hip_bfloat16 h = __float2bfloat16(f);
    return *reinterpret_cast<unsigned short*>(&h);
}

// ---------------- weight transpose + cast: in [R][C] f32 -> out [C][R] bf16 ----
__global__ __launch_bounds__(256) void transpose_cast(const float* __restrict__ in,
                                                      unsigned short* __restrict__ out,
                                                      int R, int Cc) {
    __shared__ float tile[32][33];
    int c0 = blockIdx.x * 32, r0 = blockIdx.y * 32;
    int tx = threadIdx.x, ty = threadIdx.y;      // block (32,8)
#pragma unroll
    for (int i = 0; i < 4; ++i)
        tile[ty + i*8][tx] = in[(size_t)(r0 + ty + i*8) * Cc + c0 + tx];
    __syncthreads();
#pragma unroll
    for (int i = 0; i < 4; ++i)
        out[(size_t)(c0 + ty + i*8) * R + r0 + tx] = f2bf(tile[tx][ty + i*8]);
}

// ---------------- LayerNorm: x f32 [rows][1024] -> out bf16 -------------------
__global__ __launch_bounds__(256) void ln_kernel(const float* __restrict__ x,
                                                 const float* __restrict__ g,
                                                 const float* __restrict__ be,
                                                 unsigned short* __restrict__ out) {
    int row = blockIdx.x, tid = threadIdx.x;
    const float4 xv = *(const float4*)(x + (size_t)row * Ecst + tid * 4);
    float s = xv.x + xv.y + xv.z + xv.w;
    float q = xv.x*xv.x + xv.y*xv.y + xv.z*xv.z + xv.w*xv.w;
#pragma unroll
    for (int off = 32; off; off >>= 1) { s += __shfl_xor(s, off); q += __shfl_xor(q, off); }
    __shared__ float sb[8];
    int lane = tid & 63, w = tid >> 6;
    if (lane == 0) { sb[w] = s; sb[4 + w] = q; }
    __syncthreads();
    s = sb[0] + sb[1] + sb[2] + sb[3];
    q = sb[4] + sb[5] + sb[6] + sb[7];
    float mean = s * (1.0f / Ecst);
    float var  = q * (1.0f / Ecst) - mean * mean;
    float rs = rsqrtf(var + 1e-5f);
    ushort4v o;
    const float* xp = (const float*)&xv;
#pragma unroll
    for (int u = 0; u < 4; ++u) {
        float val = (xp[u] - mean) * rs * g[tid*4+u] + be[tid*4+u];
        o[u] = f2bf(val);
    }
    *(ushort4v*)(out + (size_t)row * Ecst + tid * 4) = o;
}

// ---------------- bf16 MFMA GEMM, Bt layout [N][K], 128x128 tile --------------
// EPI 0: Ob = bf16(acc+bias)
// EPI 1: Of = resid + acc + bias                  (x1 = x + attn_proj)
// EPI 2: Ob = bf16(gelu_exact(acc+bias))
// EPI 3: v = resid + acc + bias; Of = v; Of2 = v  (x2, written twice)
#define LDT 40   // padded LDS stride (bf16 elems); 80B = 16B-aligned, conflict-free frag reads
template<int EPI>
__global__ __launch_bounds__(256) void gemm_bt(const unsigned short* __restrict__ A,
                                               const unsigned short* __restrict__ Bt,
                                               const float* __restrict__ bias,
                                               int M, int Nc, int K,
                                               unsigned short* __restrict__ Ob,
                                               float* __restrict__ Of,
                                               const float* __restrict__ resid,
                                               float* __restrict__ Of2) {
    __shared__ unsigned short As[128 * LDT];
    __shared__ unsigned short Bs[128 * LDT];
    const int tid = threadIdx.x;
    const int lane = tid & 63, wid = tid >> 6;
    const int wm = wid >> 1, wn = wid & 1;
    const int tm = blockIdx.x * 128, tn = blockIdx.y * 128;
    f32x4 acc[4][4] = {};
    for (int kt = 0; kt < K; kt += 32) {
#pragma unroll
        for (int i = 0; i < 2; ++i) {
            int c = tid + i * 256;
            int row = c >> 2, seg = c & 3;
            short8 va = *(const short8*)(A  + (size_t)(tm + row) * K + kt + seg * 8);
            short8 vb = *(const short8*)(Bt + (size_t)(tn + row) * K + kt + seg * 8);
            *(short8*)(As + row * LDT + seg * 8) = va;
            *(short8*)(Bs + row * LDT + seg * 8) = vb;
        }
        __syncthreads();
        short8 af[4], bfr[4];
#pragma unroll
        for (int mi = 0; mi < 4; ++mi)
            af[mi] = *(const short8*)(As + (wm*64 + mi*16 + (lane & 15)) * LDT + (lane >> 4) * 8);
#pragma unroll
        for (int ni = 0; ni < 4; ++ni)
            bfr[ni] = *(const short8*)(Bs + (wn*64 + ni*16 + (lane & 15)) * LDT + (lane >> 4) * 8);
#pragma unroll
        for (int mi = 0; mi < 4; ++mi)
#pragma unroll
            for (int ni = 0; ni < 4; ++ni)
                acc[mi][ni] = __builtin_amdgcn_mfma_f32_16x16x32_bf16(af[mi], bfr[ni], acc[mi][ni], 0, 0, 0);
        __syncthreads();
    }
    const int col = lane & 15, rquad = (lane >> 4) * 4;
#pragma unroll
    for (int mi = 0; mi < 4; ++mi) {
#pragma unroll
        for (int ni = 0; ni < 4; ++ni) {
            int gcol = tn + wn*64 + ni*16 + col;
            float bia = bias[gcol];
#pragma unroll
            for (int j = 0; j < 4; ++j) {
                int grow = tm + wm*64 + mi*16 + rquad + j;
                size_t idx = (size_t)grow * Nc + gcol;
                float val = acc[mi][ni][j] + bia;
                if (EPI == 0) {
                    Ob[idx] = f2bf(val);
                } else if (EPI == 1) {
                    Of[idx] = resid[idx] + val;
                } else if (EPI == 2) {
                    Ob[idx] = f2bf(0.5f * val * (1.0f + erff(val * 0.70710678118654752f)));
                } else {
                    float v2 = resid[idx] + val;
                    Of[idx] = v2; Of2[idx] = v2;
                }
            }
        }
    }
}

// ---------------- chunked sliding-window attention ----------------------------
// q,k,v bf16 [B*N][E] (col = h*64+d). One block per (b,h,chunk). 4 waves, each 16 q-rows.
// Window slot j in [0,64): prev chunk (zeros for chunk 0, UNMASKED — matches ref zero-pad).
// Slot j in [64,128): current chunk row j-64, masked unless j-64 <= i.
__global__ __launch_bounds__(256) void attn_kernel(const unsigned short* __restrict__ q,
                                                   const unsigned short* __restrict__ k,
                                                   const unsigned short* __restrict__ v,
                                                   unsigned short* __restrict__ ao) {
    __shared__ float qs[64 * 64];          // 16KB f32
    __shared__ unsigned short kT[64 * 128]; // d-major [d][j], 16KB
    __shared__ unsigned short vs[128 * 64]; // [j][d], 16KB
    __shared__ float ps[4 * 128];           // per-wave P row
    int bx = blockIdx.x;
    int c = bx & 63, h = (bx >> 6) & 15, b = bx >> 10;
    int tid = threadIdx.x, lane = tid & 63, w = tid >> 6;
    size_t base = ((size_t)b * Nn_ + c * 64) * Ecst + h * 64;
    // load q chunk -> f32 LDS
#pragma unroll
    for (int i = 0; i < 2; ++i) {
        int cc = tid + i * 256;
        int row = cc >> 3, d0 = (cc & 7) * 8;
        short8 vq = *(const short8*)(q + base + (size_t)row * Ecst + d0);
#pragma unroll
        for (int u = 0; u < 8; ++u) qs[row * 64 + d0 + u] = bf2f(((unsigned short*)&vq)[u]);
    }
    // load K (transposed) and V window
#pragma unroll
    for (int i = 0; i < 4; ++i) {
        int cc = tid + i * 256;            // 1024 chunks of 8 over 128 rows x 64 d
        int j = cc >> 3, d0 = (cc & 7) * 8;
        int srcChunk = (j < 64) ? c - 1 : c;
        int srcRow = (j < 64) ? j : j - 64;
        short8 vk = {}; short8 vv = {};
        if (srcChunk >= 0) {
            size_t sb = ((size_t)b * Nn_ + srcChunk * 64 + srcRow) * Ecst + h * 64 + d0;
            vk = *(const short8*)(k + sb);
            vv = *(const short8*)(v + sb);
        }
        *(short8*)(vs + j * 64 + d0) = vv;
#pragma unroll
        for (int u = 0; u < 8; ++u) kT[(d0 + u) * 128 + j] = ((unsigned short*)&vk)[u];
    }
    __syncthreads();
    const float scale = 0.125f;  // 1/sqrt(64)
    for (int r = 0; r < 16; ++r) {
        int i = w * 16 + r;
        float s1 = 0.f, s2 = 0.f;
#pragma unroll 8
        for (int d = 0; d < 64; ++d) {
            float qv = qs[i * 64 + d];
            s1 += qv * bf2f(kT[d * 128 + lane]);
            s2 += qv * bf2f(kT[d * 128 + 64 + lane]);
        }
        s1 *= scale; s2 *= scale;
        bool ok2 = (lane <= i);
        float mloc = fmaxf(s1, ok2 ? s2 : -1e30f);
#pragma unroll
        for (int off = 32; off; off >>= 1) mloc = fmaxf(mloc, __shfl_xor(mloc, off));
        float e1 = __expf(s1 - mloc);
        float e2 = ok2 ? __expf(s2 - mloc) : 0.f;
        float sl = e1 + e2;
#pragma unroll
        for (int off = 32; off; off >>= 1) sl += __shfl_xor(sl, off);
        float inv = 1.0f / sl;
        ps[w * 128 + lane] = e1 * inv;
        ps[w * 128 + 64 + lane] = e2 * inv;
        float acc = 0.f;
#pragma unroll 8
        for (int j = 0; j < 128; ++j)
            acc += ps[w * 128 + j] * bf2f(vs[j * 64 + lane]);
        ao[base + (size_t)i * Ecst + lane] = f2bf(acc);
    }
}

// ---------------- loss ---------------------------------------------------------
__global__ __launch_bounds__(256) void loss_partial(const float* __restrict__ x2,
                                                    const float* __restrict__ p,
                                                    float* __restrict__ partials) {
    float s = 0.f;
    for (size_t idx = (size_t)blockIdx.x * 256 + threadIdx.x; idx < BNE / 4; idx += (size_t)gridDim.x * 256) {
        float4 a = *(const float4*)(x2 + idx * 4);
        float4 b = *(const float4*)(p + idx * 4);
        float dx = a.x - b.x, dy = a.y - b.y, dz = a.z - b.z, dw = a.w - b.w;
        s += dx*dx + dy*dy + dz*dz + dw*dw;
    }
#pragma unroll
    for (int off = 32; off; off >>= 1) s += __shfl_xor(s, off);
    __shared__ float sb[4];
    int lane = threadIdx.x & 63, w = threadIdx.x >> 6;
    if (lane == 0) sb[w] = s;
    __syncthreads();
    if (threadIdx.x == 0) partials[blockIdx.x] = sb[0] + sb[1] + sb[2] + sb[3];
}

__global__ __launch_bounds__(256) void loss_final(const float* __restrict__ partials,
                                                  float* __restrict__ out) {
    float s = 0.f;
    for (int i = threadIdx.x; i < 2048; i += 256) s += partials[i];
#pragma unroll
    for (int off = 32; off; off >>= 1) s += __shfl_xor(s, off);
    __shared__ float sb[4];
    int lane = threadIdx.x & 63, w = threadIdx.x >> 6;
    if (lane == 0) sb[w] = s;
    __syncthreads();
    if (threadIdx.x == 0) out[0] = (sb[0] + sb[1] + sb[2] + sb[3]) * (1.0f / (float)BNE);
}

extern "C" void kernel_launch(void* const* d_in, const int* in_sizes, int n_in,
                              void* d_out, int out_size, void* d_ws, size_t ws_size,
                              hipStream_t stream) {
    const float* x     = (const float*)d_in[0];
    const float* p     = (const float*)d_in[1];
    const float* wq    = (const float*)d_in[2];
    const float* bq    = (const float*)d_in[3];
    const float* wk    = (const float*)d_in[4];
    const float* bk    = (const float*)d_in[5];
    const float* wv    = (const float*)d_in[6];
    const float* bv    = (const float*)d_in[7];
    const float* wo    = (const float*)d_in[8];
    const float* bo    = (const float*)d_in[9];
    const float* w1    = (const float*)d_in[10];
    const float* b1    = (const float*)d_in[11];
    const float* w2    = (const float*)d_in[12];
    const float* b2    = (const float*)d_in[13];
    const float* g1    = (const float*)d_in[14];
    const float* beta1 = (const float*)d_in[15];
    const float* g2    = (const float*)d_in[16];
    const float* beta2 = (const float*)d_in[17];

    char* ws = (char*)d_ws;
    size_t off = 0;
    auto alloc = [&](size_t bytes) { void* pp = ws + off; off += (bytes + 255) & ~(size_t)255; return pp; };
    unsigned short* wqT = (unsigned short*)alloc((size_t)Ecst * Ecst * 2);
    unsigned short* wkT = (unsigned short*)alloc((size_t)Ecst * Ecst * 2);
    unsigned short* wvT = (unsigned short*)alloc((size_t)Ecst * Ecst * 2);
    unsigned short* woT = (unsigned short*)alloc((size_t)Ecst * Ecst * 2);
    unsigned short* w1T = (unsigned short*)alloc((size_t)4 * Ecst * Ecst * 2);
    unsigned short* w2T = (unsigned short*)alloc((size_t)4 * Ecst * Ecst * 2);
    unsigned short* xn  = (unsigned short*)alloc((size_t)Mrows * Ecst * 2);  // reused as h after LN2
    unsigned short* qb  = (unsigned short*)alloc((size_t)Mrows * Ecst * 2);
    unsigned short* kb  = (unsigned short*)alloc((size_t)Mrows * Ecst * 2);
    unsigned short* vb  = (unsigned short*)alloc((size_t)Mrows * Ecst * 2);
    unsigned short* aob = (unsigned short*)alloc((size_t)Mrows * Ecst * 2);
    unsigned short* ff1 = (unsigned short*)alloc((size_t)Mrows * 4 * Ecst * 2);
    float* partials     = (float*)alloc(2048 * 4);

    float* x1 = (float*)d_out;                    // [0, BNE): x1 then x2 (copy 0)
    float* out2 = (float*)d_out + BNE;            // x2 (copy 1)
    float* lossp = (float*)d_out + 2 * (size_t)BNE;

    dim3 tb(32, 8);
    transpose_cast<<<dim3(32, 32),  tb, 0, stream>>>(wq, wqT, Ecst, Ecst);
    transpose_cast<<<dim3(32, 32),  tb, 0, stream>>>(wk, wkT, Ecst, Ecst);
    transpose_cast<<<dim3(32, 32),  tb, 0, stream>>>(wv, wvT, Ecst, Ecst);
    transpose_cast<<<dim3(32, 32),  tb, 0, stream>>>(wo, woT, Ecst, Ecst);
    transpose_cast<<<dim3(128, 32), tb, 0, stream>>>(w1, w1T, Ecst, 4 * Ecst);
    transpose_cast<<<dim3(32, 128), tb, 0, stream>>>(w2, w2T, 4 * Ecst, Ecst);

    ln_kernel<<<Mrows, 256, 0, stream>>>(x, g1, beta1, xn);

    dim3 gq(Mrows / 128, Ecst / 128);
    gemm_bt<0><<<gq, 256, 0, stream>>>(xn, wqT, bq, Mrows, Ecst, Ecst, qb, nullptr, nullptr, nullptr);
    gemm_bt<0><<<gq, 256, 0, stream>>>(xn, wkT, bk, Mrows, Ecst, Ecst, kb, nullptr, nullptr, nullptr);
    gemm_bt<0><<<gq, 256, 0, stream>>>(xn, wvT, bv, Mrows, Ecst, Ecst, vb, nullptr, nullptr, nullptr);

    attn_kernel<<<Bb * Hh * (Nn_ / Cc_), 256, 0, stream>>>(qb, kb, vb, aob);

    gemm_bt<1><<<gq, 256, 0, stream>>>(aob, woT, bo, Mrows, Ecst, Ecst, nullptr, x1, x, nullptr);

    ln_kernel<<<Mrows, 256, 0, stream>>>(x1, g2, beta2, xn);

    gemm_bt<2><<<dim3(Mrows / 128, 4 * Ecst / 128), 256, 0, stream>>>(xn, w1T, b1, Mrows, 4 * Ecst, Ecst, ff1, nullptr, nullptr, nullptr);

    gemm_bt<3><<<gq, 256, 0, stream>>>(ff1, w2T, b2, Mrows, Ecst, 4 * Ecst, nullptr, x1, x1, out2);

    loss_partial<<<2048, 256, 0, stream>>>((const float*)d_out, p, partials);
    loss_final<<<1, 256, 0, stream>>>(partials, lossp);
}

// Round 2
// 922.185 us; speedup vs baseline: 1.3740x; 1.3740x over previous
//
#include <hip/hip_runtime.h>
#include <hip/hip_bf16.h>

// Problem constants
#define Ecst 1024
#define Hh 16
#define Dd 64
#define Cc_ 64
#define Bb 4
#define Nn_ 4096
#define Mrows (Bb*Nn_)          // 16384 token rows
#define BNE (Bb*Nn_*Ecst)       // 16,777,216

typedef __attribute__((ext_vector_type(4))) float f32x4;
typedef __attribute__((ext_vector_type(8))) short short8;
typedef __attribute__((ext_vector_type(4))) unsigned short ushort4v;

__device__ __forceinline__ float bf2f(unsigned short u) {
    union { float f; unsigned int i; } x; x.i = ((unsigned int)u) << 16; return x.f;
}
__device__ __forceinline__ unsigned short f2bf(float f) {
    __hip_bfloat16 h = __float2bfloat16(f);
    return *reinterpret_cast<unsigned short*>(&h);
}
// async global->LDS, 16B per lane. lds ptr must be wave-uniform base.
__device__ __forceinline__ void glds16(const unsigned short* g, unsigned short* l) {
    __builtin_amdgcn_global_load_lds(
        (const __attribute__((address_space(1))) unsigned int*)g,
        (__attribute__((address_space(3))) unsigned int*)l, 16, 0, 0);
}

// ---------------- weight transpose + cast: in [R][C] f32 -> out [C][R] bf16 ----
__global__ __launch_bounds__(256) void transpose_cast(const float* __restrict__ in,
                                                      unsigned short* __restrict__ out,
                                                      int R, int Cc) {
    __shared__ float tile[32][33];
    int c0 = blockIdx.x * 32, r0 = blockIdx.y * 32;
    int tx = threadIdx.x, ty = threadIdx.y;      // block (32,8)
#pragma unroll
    for (int i = 0; i < 4; ++i)
        tile[ty + i*8][tx] = in[(size_t)(r0 + ty + i*8) * Cc + c0 + tx];
    __syncthreads();
#pragma unroll
    for (int i = 0; i < 4; ++i)
        out[(size_t)(c0 + ty + i*8) * R + r0 + tx] = f2bf(tile[tx][ty + i*8]);
}

// ---------------- LayerNorm: x f32 [rows][1024] -> out bf16 -------------------
__global__ __launch_bounds__(256) void ln_kernel(const float* __restrict__ x,
                                                 const float* __restrict__ g,
                                                 const float* __restrict__ be,
                                                 unsigned short* __restrict__ out) {
    int row = blockIdx.x, tid = threadIdx.x;
    const float4 xv = *(const float4*)(x + (size_t)row * Ecst + tid * 4);
    float s = xv.x + xv.y + xv.z + xv.w;
    float q = xv.x*xv.x + xv.y*xv.y + xv.z*xv.z + xv.w*xv.w;
#pragma unroll
    for (int off = 32; off; off >>= 1) { s += __shfl_xor(s, off); q += __shfl_xor(q, off); }
    __shared__ float sb[8];
    int lane = tid & 63, w = tid >> 6;
    if (lane == 0) { sb[w] = s; sb[4 + w] = q; }
    __syncthreads();
    s = sb[0] + sb[1] + sb[2] + sb[3];
    q = sb[4] + sb[5] + sb[6] + sb[7];
    float mean = s * (1.0f / Ecst);
    float var  = q * (1.0f / Ecst) - mean * mean;
    float rs = rsqrtf(var + 1e-5f);
    ushort4v o;
    const float* xp = (const float*)&xv;
#pragma unroll
    for (int u = 0; u < 4; ++u) {
        float val = (xp[u] - mean) * rs * g[tid*4+u] + be[tid*4+u];
        o[u] = f2bf(val);
    }
    *(ushort4v*)(out + (size_t)row * Ecst + tid * 4) = o;
}

// ---------------- bf16 MFMA GEMM, m97 structure -------------------------------
// Bt layout [N][K]. 128x128 tile, BK=32, linear LDS + global_load_lds width 16.
// EPI 0: Ob = bf16(acc+bias)
// EPI 1: Of = resid + acc + bias                  (x1 = x + attn_proj)
// EPI 2: Ob = bf16(gelu_exact(acc+bias))
// EPI 3: v = resid + acc + bias; Of = v; Of2 = v  (x2, written twice)
template<int EPI>
__global__ __launch_bounds__(256) void gemm_bt(const unsigned short* __restrict__ A,
                                               const unsigned short* __restrict__ Bt,
                                               const float* __restrict__ bias,
                                               int M, int Nc, int K,
                                               unsigned short* __restrict__ Ob,
                                               float* __restrict__ Of,
                                               const float* __restrict__ resid,
                                               float* __restrict__ Of2) {
    __shared__ unsigned short As[128 * 32];
    __shared__ unsigned short Bs[128 * 32];
    const int tid = threadIdx.x;
    const int lane = tid & 63, wid = tid >> 6;
    const int wm = wid >> 1, wn = wid & 1;
    const int tm = blockIdx.x * 128, tn = blockIdx.y * 128;
    // slot s covers LDS bytes s*16 = element s*8: row=s>>2, kseg=s&3 (8 bf16 each)
    const int s0 = wid * 128 + lane;
    const int s1 = s0 + 64;
    const unsigned short* gA0 = A  + (size_t)(tm + (s0 >> 2)) * K + (s0 & 3) * 8;
    const unsigned short* gA1 = A  + (size_t)(tm + (s1 >> 2)) * K + (s1 & 3) * 8;
    const unsigned short* gB0 = Bt + (size_t)(tn + (s0 >> 2)) * K + (s0 & 3) * 8;
    const unsigned short* gB1 = Bt + (size_t)(tn + (s1 >> 2)) * K + (s1 & 3) * 8;
    unsigned short* lA0 = As + (size_t)wid * 1024;
    unsigned short* lA1 = As + (size_t)wid * 1024 + 512;
    unsigned short* lB0 = Bs + (size_t)wid * 1024;
    unsigned short* lB1 = Bs + (size_t)wid * 1024 + 512;
    f32x4 acc[4][4] = {};
    for (int kt = 0; kt < K; kt += 32) {
        glds16(gA0 + kt, lA0);
        glds16(gA1 + kt, lA1);
        glds16(gB0 + kt, lB0);
        glds16(gB1 + kt, lB1);
        __syncthreads();   // compiler emits vmcnt(0) drain before s_barrier
        short8 af[4], bfr[4];
#pragma unroll
        for (int mi = 0; mi < 4; ++mi)
            af[mi] = *(const short8*)(As + (wm*64 + mi*16 + (lane & 15)) * 32 + (lane >> 4) * 8);
#pragma unroll
        for (int ni = 0; ni < 4; ++ni)
            bfr[ni] = *(const short8*)(Bs + (wn*64 + ni*16 + (lane & 15)) * 32 + (lane >> 4) * 8);
#pragma unroll
        for (int mi = 0; mi < 4; ++mi)
#pragma unroll
            for (int ni = 0; ni < 4; ++ni)
                acc[mi][ni] = __builtin_amdgcn_mfma_f32_16x16x32_bf16(af[mi], bfr[ni], acc[mi][ni], 0, 0, 0);
        __syncthreads();
    }
    const int col = lane & 15, rquad = (lane >> 4) * 4;
#pragma unroll
    for (int mi = 0; mi < 4; ++mi) {
#pragma unroll
        for (int ni = 0; ni < 4; ++ni) {
            int gcol = tn + wn*64 + ni*16 + col;
            float bia = bias[gcol];
#pragma unroll
            for (int j = 0; j < 4; ++j) {
                int grow = tm + wm*64 + mi*16 + rquad + j;
                size_t idx = (size_t)grow * Nc + gcol;
                float val = acc[mi][ni][j] + bia;
                if (EPI == 0) {
                    Ob[idx] = f2bf(val);
                } else if (EPI == 1) {
                    Of[idx] = resid[idx] + val;
                } else if (EPI == 2) {
                    Ob[idx] = f2bf(0.5f * val * (1.0f + erff(val * 0.70710678118654752f)));
                } else {
                    float v2 = resid[idx] + val;
                    Of[idx] = v2; Of2[idx] = v2;
                }
            }
        }
    }
}

// ---------------- chunked sliding-window attention (MFMA) ---------------------
// One block per (b,h,chunk). 4 waves, each computes 16 q-rows.
// Window: slots [0,64) = prev chunk (zeros for chunk 0, UNMASKED per reference
// zero-pad); slots [64,128) = current chunk, masked unless col-64 <= row.
// XOR-swizzled LDS (G4): 128B-stride rows are otherwise a 16-32-way conflict.
#define QS_OFF(r,d0) ((r)*64  + ((((d0)>>3) ^ ((r)&7))  << 3))
#define KS_OFF(j,d0) ((j)*64  + ((((d0)>>3) ^ ((j)&7))  << 3))
#define VT_OFF(d,j0) ((d)*128 + ((((j0)>>3) ^ ((d)&15)) << 3))
#define PS_OFF(r,c0) ((r)*128 + ((((c0)>>3) ^ ((r)&15)) << 3))
__global__ __launch_bounds__(256) void attn_mfma(const unsigned short* __restrict__ q,
                                                 const unsigned short* __restrict__ k,
                                                 const unsigned short* __restrict__ v,
                                                 unsigned short* __restrict__ ao) {
    __shared__ unsigned short qs[64 * 64];    // Q row-major, swizzled
    __shared__ unsigned short ks[128 * 64];   // K window row-major, swizzled
    __shared__ unsigned short vT[64 * 128];   // V^T [d][j], swizzled
    __shared__ unsigned short ps[64 * 128];   // P row-major, swizzled
    int bx = blockIdx.x;
    int c = bx & 63, h = (bx >> 6) & 15, b = bx >> 10;
    int tid = threadIdx.x, lane = tid & 63, w = tid >> 6;
    size_t base = ((size_t)b * Nn_ + c * 64) * Ecst + h * 64;
    // stage Q
#pragma unroll
    for (int i = 0; i < 2; ++i) {
        int cc = tid + i * 256;
        int row = cc >> 3, d0 = (cc & 7) * 8;
        short8 vq = *(const short8*)(q + base + (size_t)row * Ecst + d0);
        *(short8*)(qs + QS_OFF(row, d0)) = vq;
    }
    // stage K row-major + V transposed
#pragma unroll
    for (int i = 0; i < 4; ++i) {
        int cc = tid + i * 256;
        int j = cc >> 3, d0 = (cc & 7) * 8;
        short8 vk = {}; short8 vv = {};
        if (c > 0 || j >= 64) {
            int srcRow = (j < 64) ? (c - 1) * 64 + j : c * 64 + (j - 64);
            size_t sb = ((size_t)b * Nn_ + srcRow) * Ecst + h * 64 + d0;
            vk = *(const short8*)(k + sb);
            vv = *(const short8*)(v + sb);
        }
        *(short8*)(ks + KS_OFF(j, d0)) = vk;
#pragma unroll
        for (int u = 0; u < 8; ++u)
            vT[VT_OFF(d0 + u, j & ~7) + (j & 7)] = ((unsigned short*)&vv)[u];
    }
    __syncthreads();
    // QK^T: per wave M=16 (rows w*16..+16), N=128, K=64 -> 16 MFMAs
    const int rA = w * 16 + (lane & 15);
    const int ksel = (lane >> 4) * 8;
    f32x4 s[8] = {};
#pragma unroll
    for (int kk = 0; kk < 2; ++kk) {
        short8 aq = *(const short8*)(qs + QS_OFF(rA, kk * 32 + ksel));
#pragma unroll
        for (int ni = 0; ni < 8; ++ni) {
            int j = ni * 16 + (lane & 15);
            short8 bk = *(const short8*)(ks + KS_OFF(j, kk * 32 + ksel));
            s[ni] = __builtin_amdgcn_mfma_f32_16x16x32_bf16(aq, bk, s[ni], 0, 0, 0);
        }
    }
    // row softmax: C/D layout row=(lane>>4)*4+jr -> 16-lane groups share a row
    float inv[4];
    const int rq = (lane >> 4) * 4;
#pragma unroll
    for (int jr = 0; jr < 4; ++jr) {
        int i = w * 16 + rq + jr;
        float vals[8]; float mx = -1e30f;
#pragma unroll
        for (int ni = 0; ni < 8; ++ni) {
            int colw = ni * 16 + (lane & 15);
            bool valid = (colw < 64) || (colw - 64 <= i);
            float vv = valid ? s[ni][jr] * 0.125f : -1e30f;
            vals[ni] = vv;
            mx = fmaxf(mx, vv);
        }
#pragma unroll
        for (int off = 8; off; off >>= 1) mx = fmaxf(mx, __shfl_xor(mx, off));
        float sum = 0.f;
#pragma unroll
        for (int ni = 0; ni < 8; ++ni) {
            float e = (vals[ni] > -1e29f) ? __expf(vals[ni] - mx) : 0.f;
            vals[ni] = e; sum += e;
        }
#pragma unroll
        for (int off = 8; off; off >>= 1) sum += __shfl_xor(sum, off);
        inv[jr] = 1.0f / sum;
        int r = w * 16 + rq + jr;
#pragma unroll
        for (int ni = 0; ni < 8; ++ni) {
            int colw = ni * 16 + (lane & 15);
            ps[PS_OFF(r, colw & ~7) + (colw & 7)] = f2bf(vals[ni]);
        }
    }
    __syncthreads();
    // PV: per wave M=16, N=64, K=128 -> 16 MFMAs
    f32x4 o[4] = {};
#pragma unroll
    for (int kk = 0; kk < 4; ++kk) {
        short8 ap = *(const short8*)(ps + PS_OFF(rA, kk * 32 + ksel));
#pragma unroll
        for (int ni = 0; ni < 4; ++ni) {
            int d = ni * 16 + (lane & 15);
            short8 bv = *(const short8*)(vT + VT_OFF(d, kk * 32 + ksel));
            o[ni] = __builtin_amdgcn_mfma_f32_16x16x32_bf16(ap, bv, o[ni], 0, 0, 0);
        }
    }
#pragma unroll
    for (int ni = 0; ni < 4; ++ni) {
#pragma unroll
        for (int jr = 0; jr < 4; ++jr) {
            int row = w * 16 + rq + jr;
            int d = ni * 16 + (lane & 15);
            ao[base + (size_t)row * Ecst + d] = f2bf(o[ni][jr] * inv[jr]);
        }
    }
}

// ---------------- loss ---------------------------------------------------------
__global__ __launch_bounds__(256) void loss_partial(const float* __restrict__ x2,
                                                    const float* __restrict__ p,
                                                    float* __restrict__ partials) {
    float s = 0.f;
    for (size_t idx = (size_t)blockIdx.x * 256 + threadIdx.x; idx < BNE / 4; idx += (size_t)gridDim.x * 256) {
        float4 a = *(const float4*)(x2 + idx * 4);
        float4 b = *(const float4*)(p + idx * 4);
        float dx = a.x - b.x, dy = a.y - b.y, dz = a.z - b.z, dw = a.w - b.w;
        s += dx*dx + dy*dy + dz*dz + dw*dw;
    }
#pragma unroll
    for (int off = 32; off; off >>= 1) s += __shfl_xor(s, off);
    __shared__ float sb[4];
    int lane = threadIdx.x & 63, w = threadIdx.x >> 6;
    if (lane == 0) sb[w] = s;
    __syncthreads();
    if (threadIdx.x == 0) partials[blockIdx.x] = sb[0] + sb[1] + sb[2] + sb[3];
}

__global__ __launch_bounds__(256) void loss_final(const float* __restrict__ partials,
                                                  float* __restrict__ out) {
    float s = 0.f;
    for (int i = threadIdx.x; i < 2048; i += 256) s += partials[i];
#pragma unroll
    for (int off = 32; off; off >>= 1) s += __shfl_xor(s, off);
    __shared__ float sb[4];
    int lane = threadIdx.x & 63, w = threadIdx.x >> 6;
    if (lane == 0) sb[w] = s;
    __syncthreads();
    if (threadIdx.x == 0) out[0] = (sb[0] + sb[1] + sb[2] + sb[3]) * (1.0f / (float)BNE);
}

extern "C" void kernel_launch(void* const* d_in, const int* in_sizes, int n_in,
                              void* d_out, int out_size, void* d_ws, size_t ws_size,
                              hipStream_t stream) {
    const float* x     = (const float*)d_in[0];
    const float* p     = (const float*)d_in[1];
    const float* wq    = (const float*)d_in[2];
    const float* bq    = (const float*)d_in[3];
    const float* wk    = (const float*)d_in[4];
    const float* bk    = (const float*)d_in[5];
    const float* wv    = (const float*)d_in[6];
    const float* bv    = (const float*)d_in[7];
    const float* wo    = (const float*)d_in[8];
    const float* bo    = (const float*)d_in[9];
    const float* w1    = (const float*)d_in[10];
    const float* b1    = (const float*)d_in[11];
    const float* w2    = (const float*)d_in[12];
    const float* b2    = (const float*)d_in[13];
    const float* g1    = (const float*)d_in[14];
    const float* beta1 = (const float*)d_in[15];
    const float* g2    = (const float*)d_in[16];
    const float* beta2 = (const float*)d_in[17];

    char* ws = (char*)d_ws;
    size_t off = 0;
    auto alloc = [&](size_t bytes) { void* pp = ws + off; off += (bytes + 255) & ~(size_t)255; return pp; };
    unsigned short* wqT = (unsigned short*)alloc((size_t)Ecst * Ecst * 2);
    unsigned short* wkT = (unsigned short*)alloc((size_t)Ecst * Ecst * 2);
    unsigned short* wvT = (unsigned short*)alloc((size_t)Ecst * Ecst * 2);
    unsigned short* woT = (unsigned short*)alloc((size_t)Ecst * Ecst * 2);
    unsigned short* w1T = (unsigned short*)alloc((size_t)4 * Ecst * Ecst * 2);
    unsigned short* w2T = (unsigned short*)alloc((size_t)4 * Ecst * Ecst * 2);
    unsigned short* xn  = (unsigned short*)alloc((size_t)Mrows * Ecst * 2);  // reused as h after LN2
    unsigned short* qb  = (unsigned short*)alloc((size_t)Mrows * Ecst * 2);
    unsigned short* kb  = (unsigned short*)alloc((size_t)Mrows * Ecst * 2);
    unsigned short* vb  = (unsigned short*)alloc((size_t)Mrows * Ecst * 2);
    unsigned short* aob = (unsigned short*)alloc((size_t)Mrows * Ecst * 2);
    unsigned short* ff1 = (unsigned short*)alloc((size_t)Mrows * 4 * Ecst * 2);
    float* partials     = (float*)alloc(2048 * 4);

    float* x1 = (float*)d_out;                    // [0, BNE): x1 then x2 (copy 0)
    float* out2 = (float*)d_out + BNE;            // x2 (copy 1)
    float* lossp = (float*)d_out + 2 * (size_t)BNE;

    dim3 tb(32, 8);
    transpose_cast<<<dim3(32, 32),  tb, 0, stream>>>(wq, wqT, Ecst, Ecst);
    transpose_cast<<<dim3(32, 32),  tb, 0, stream>>>(wk, wkT, Ecst, Ecst);
    transpose_cast<<<dim3(32, 32),  tb, 0, stream>>>(wv, wvT, Ecst, Ecst);
    transpose_cast<<<dim3(32, 32),  tb, 0, stream>>>(wo, woT, Ecst, Ecst);
    transpose_cast<<<dim3(128, 32), tb, 0, stream>>>(w1, w1T, Ecst, 4 * Ecst);
    transpose_cast<<<dim3(32, 128), tb, 0, stream>>>(w2, w2T, 4 * Ecst, Ecst);

    ln_kernel<<<Mrows, 256, 0, stream>>>(x, g1, beta1, xn);

    dim3 gq(Mrows / 128, Ecst / 128);
    gemm_bt<0><<<gq, 256, 0, stream>>>(xn, wqT, bq, Mrows, Ecst, Ecst, qb, nullptr, nullptr, nullptr);
    gemm_bt<0><<<gq, 256, 0, stream>>>(xn, wkT, bk, Mrows, Ecst, Ecst, kb, nullptr, nullptr, nullptr);
    gemm_bt<0><<<gq, 256, 0, stream>>>(xn, wvT, bv, Mrows, Ecst, Ecst, vb, nullptr, nullptr, nullptr);

    attn_mfma<<<Bb * Hh * (Nn_ / Cc_), 256, 0, stream>>>(qb, kb, vb, aob);

    gemm_bt<1><<<gq, 256, 0, stream>>>(aob, woT, bo, Mrows, Ecst, Ecst, nullptr, x1, x, nullptr);

    ln_kernel<<<Mrows, 256, 0, stream>>>(x1, g2, beta2, xn);

    gemm_bt<2><<<dim3(Mrows / 128, 4 * Ecst / 128), 256, 0, stream>>>(xn, w1T, b1, Mrows, 4 * Ecst, Ecst, ff1, nullptr, nullptr, nullptr);

    gemm_bt<3><<<gq, 256, 0, stream>>>(ff1, w2T, b2, Mrows, Ecst, 4 * Ecst, nullptr, x1, x1, out2);

    loss_partial<<<2048, 256, 0, stream>>>((const float*)d_out, p, partials);
    loss_final<<<1, 256, 0, stream>>>(partials, lossp);
}